// Round 20
// baseline (276.882 us; speedup 1.0000x reference)
//
#include <hip/hip_runtime.h>
#include <hip/hip_bf16.h>

typedef __bf16 bf16_t;
typedef __bf16 bf16x8 __attribute__((ext_vector_type(8)));
typedef float  f32x4  __attribute__((ext_vector_type(4)));

#define DK 1024   // d_in  (K)
#define DN 1024   // d_out (N)
#define RNK 32
#define BM 64
#define BN 256
#define BK 32
#define NKT 32

// ---- Pass 1: W_eff = W + C @ V_r^T, bf16, PRE-SWIZZLED (R8 16KB-chunk) -----
// Chunks [bn(4)][kt(32)] of 16KB: byte = rloc*64 + ((seg^((rloc>>1)&3))<<4).
__global__ void weff_kernel(const float* __restrict__ W,
                            const float* __restrict__ Vr,
                            const float* __restrict__ C,
                            bf16_t* __restrict__ WeffSw)
{
    const int o  = blockIdx.x;
    const int g  = threadIdx.x;
    const int d0 = g * 8;

    f32x4 cv[8];
#pragma unroll
    for (int q = 0; q < 8; ++q) cv[q] = *(const f32x4*)(C + o * RNK + q * 4);

    const f32x4* wrow = (const f32x4*)(W + (size_t)o * DK + d0);
    f32x4 w0 = wrow[0], w1 = wrow[1];
    float acc[8];
#pragma unroll
    for (int e = 0; e < 4; ++e) { acc[e] = w0[e]; acc[4 + e] = w1[e]; }

#pragma unroll
    for (int e = 0; e < 8; ++e) {
        const f32x4* vre = (const f32x4*)(Vr + (size_t)(d0 + e) * RNK);
        float s = 0.f;
#pragma unroll
        for (int q = 0; q < 8; ++q) {
            f32x4 v = vre[q];
            s += cv[q][0] * v[0] + cv[q][1] * v[1] + cv[q][2] * v[2] + cv[q][3] * v[3];
        }
        acc[e] += s;
    }

    bf16x8 out;
#pragma unroll
    for (int e = 0; e < 8; ++e) out[e] = (bf16_t)acc[e];

    const int bn = o >> 8, rloc = o & 255;
    const int kt = d0 >> 5, seg = (d0 >> 3) & 3;
    const int sw = seg ^ ((rloc >> 1) & 3);
    const size_t byte = (size_t)(bn * 32 + kt) * 16384 + rloc * 64 + (sw << 4);
    *(bf16x8*)((char*)WeffSw + byte) = out;
}

// ---- Pass 2: fp32-direct all-DMA, depth-2 counted, 2 blocks/CU -------------
// 64x256 tile, 4 waves of 64x64 (acc 64 AGPR). A: fp32 DMA w/ per-lane
// swizzled src (R17); B: bf16 pre-swizzled chunks. 3-cyclic 72KB LDS ->
// 2 independent blocks/CU overlap each other's DMA-latency stalls.
__global__ __launch_bounds__(256, 2) void corrlin_gemm_dma(
    const float* __restrict__ X, const bf16_t* __restrict__ WeffSw,
    const float* __restrict__ bias, float* __restrict__ Out)
{
    __shared__ __align__(16) char smem[73728];
    char* Af0 = smem;                 // fp32 A tiles, 8KB each
    char* Af1 = smem + 8192;
    char* Af2 = smem + 16384;
    char* Bq0 = smem + 24576;         // bf16 B tiles, 16KB each
    char* Bq1 = smem + 40960;
    char* Bq2 = smem + 57344;

    const int tid = threadIdx.x;
    const int b0  = blockIdx.x;
    const int L  = (b0 & 7) * 512 + (b0 >> 3);   // XCD-bijective, nwg=4096
    const int bm = L >> 2;            // 1024 m-tiles
    const int bn = L & 3;             // 4 n-tiles (consecutive share x panel)
    const int m0 = bm * BM;

    const int lane = tid & 63;
    const int wn   = tid >> 6;        // 0..3

    f32x4 acc[4][4] = {};             // 64 AGPR

    // A DMA: 512 granules of 16B. dest d -> row=d>>3, slot=d&7 holds source
    // granule g=(d&7)^(row&7): src = x[m0+row][kt*32 + g*4 .. +4).
    auto issueA = [&](int kt, char* Af) {
#pragma unroll
        for (int c = 0; c < 2; ++c) {
            const int d   = wn * 128 + c * 64 + lane;
            const int row = d >> 3;
            const int g   = (d & 7) ^ (row & 7);
            const float* src = X + (size_t)(m0 + row) * DK + kt * 32 + g * 4;
            __builtin_amdgcn_global_load_lds(
                (const __attribute__((address_space(1))) void*)src,
                (__attribute__((address_space(3))) void*)(Af + wn * 2048 + c * 1024),
                16, 0, 0);
        }
    };
    auto issueB = [&](int kt, char* Bb) {
        const char* g = (const char*)WeffSw + (size_t)(bn * 32 + kt) * 16384;
#pragma unroll
        for (int c = 0; c < 4; ++c) {
            const int lin = wn * 4096 + c * 1024;
            __builtin_amdgcn_global_load_lds(
                (const __attribute__((address_space(1))) void*)(g + lin + lane * 16),
                (__attribute__((address_space(3))) void*)(Bb + lin),
                16, 0, 0);
        }
    };
    auto readB = [&](const char* Bc, bf16x8* bfr) {
        const int kb = lane >> 4;
#pragma unroll
        for (int nf = 0; nf < 4; ++nf) {
            const int row = wn * 64 + nf * 16 + (lane & 15);
            bfr[nf] = *(const bf16x8*)(Bc + row * 64 + ((kb ^ ((row >> 1) & 3)) << 4));
        }
    };
    auto compute = [&](const char* Af, const bf16x8* bfr) {
        bf16x8 af[4];
        const int kb = lane >> 4;
#pragma unroll
        for (int i = 0; i < 4; ++i) {
            const int row = i * 16 + (lane & 15);
            const int rs = row & 7;
            f32x4 v0 = *(const f32x4*)(Af + row * 128 + (((2 * kb)     ^ rs) << 4));
            f32x4 v1 = *(const f32x4*)(Af + row * 128 + (((2 * kb + 1) ^ rs) << 4));
#pragma unroll
            for (int j = 0; j < 4; ++j) { af[i][j] = (bf16_t)v0[j]; af[i][4 + j] = (bf16_t)v1[j]; }
        }
        __builtin_amdgcn_s_setprio(1);
#pragma unroll
        for (int mf = 0; mf < 4; ++mf)
#pragma unroll
            for (int nf = 0; nf < 4; ++nf)
                acc[mf][nf] = __builtin_amdgcn_mfma_f32_16x16x32_bf16(
                    af[mf], bfr[nf], acc[mf][nf], 0, 0, 0);
        __builtin_amdgcn_s_setprio(0);
    };

    // steady-state iteration (t+2 <= 31): issue t+2 (6 ops), compute t,
    // vmcnt(6) drains tile t+1 (issued a full iteration ago).
    auto iterM = [&](int t, const char* Afc, const char* Bc, char* AfN, char* BN2) {
        issueB(t + 2, BN2);
        issueA(t + 2, AfN);
        bf16x8 bfr[4];
        readB(Bc, bfr);
        compute(Afc, bfr);
        asm volatile("s_waitcnt vmcnt(6) lgkmcnt(0)" ::: "memory");
        __builtin_amdgcn_s_barrier();
    };

    // ---- prologue: tiles 0,1 issued; tile 0 landed -------------------------
    issueB(0, Bq0); issueA(0, Af0);
    issueB(1, Bq1); issueA(1, Af1);
    asm volatile("s_waitcnt vmcnt(6)" ::: "memory");
    __builtin_amdgcn_s_barrier();

    // main: t = 0..29, 3-cyclic, guard-free
    for (int t = 0; t < 30; t += 3) {
        iterM(t,     Af0, Bq0, Af2, Bq2);
        iterM(t + 1, Af1, Bq1, Af0, Bq0);
        iterM(t + 2, Af2, Bq2, Af1, Bq1);
    }
    // t = 30: drain tile 31
    {
        bf16x8 bfr[4];
        readB(Bq0, bfr);
        compute(Af0, bfr);
        asm volatile("s_waitcnt vmcnt(0) lgkmcnt(0)" ::: "memory");
        __builtin_amdgcn_s_barrier();
    }
    // t = 31
    {
        bf16x8 bfr[4];
        readB(Bq1, bfr);
        compute(Af1, bfr);
    }
    __syncthreads();                 // LDS free for epilogue reuse

    // ---- epilogue: per-wave LDS transpose -> full-line f32x4 stores --------
    float* tb = (float*)smem + wn * 1280;   // 16x80 f32 per wave (20KB)
    const int nbase = bn * BN + wn * 64;
    float bv[4];
#pragma unroll
    for (int nf = 0; nf < 4; ++nf) bv[nf] = bias[nbase + nf * 16 + (lane & 15)];

#pragma unroll
    for (int mf = 0; mf < 4; ++mf) {
#pragma unroll
        for (int nf = 0; nf < 4; ++nf)
#pragma unroll
            for (int j = 0; j < 4; ++j) {
                const int r = (lane >> 4) * 4 + j;
                const int c = nf * 16 + (lane & 15);
                tb[r * 80 + c] = acc[mf][nf][j] + bv[nf];
            }
        __syncthreads();
#pragma unroll
        for (int jj = 0; jj < 4; ++jj) {
            const int rr = jj * 4 + (lane >> 4);
            const int cc = (lane & 15) * 4;
            f32x4 v = *(const f32x4*)&tb[rr * 80 + cc];
            *(f32x4*)&Out[(size_t)(m0 + mf * 16 + rr) * DN + nbase + cc] = v;
        }
        __syncthreads();
    }
}

extern "C" void kernel_launch(void* const* d_in, const int* in_sizes, int n_in,
                              void* d_out, int out_size, void* d_ws, size_t ws_size,
                              hipStream_t stream) {
    const float* x  = (const float*)d_in[0];
    const float* W  = (const float*)d_in[1];
    const float* b  = (const float*)d_in[2];
    const float* Vr = (const float*)d_in[3];
    const float* C  = (const float*)d_in[4];
    float* out = (float*)d_out;

    const int M = in_sizes[0] / DK;            // 65536
    bf16_t* WeffSw = (bf16_t*)d_ws;            // 2 MB pre-swizzled W_eff

    weff_kernel<<<DN, 128, 0, stream>>>(W, Vr, C, WeffSw);

    const int mtiles = M / BM;                 // 1024
    const int nwg = mtiles * (DN / BN);        // 4096
    corrlin_gemm_dma<<<nwg, 256, 0, stream>>>(x, WeffSw, b, out);
}

// Round 21
// 226.103 us; speedup vs baseline: 1.2246x; 1.2246x over previous
//
#include <hip/hip_runtime.h>
#include <hip/hip_bf16.h>

typedef __bf16 bf16_t;
typedef __bf16 bf16x8 __attribute__((ext_vector_type(8)));
typedef float  f32x4  __attribute__((ext_vector_type(4)));

#define DK 1024   // d_in  (K)
#define DN 1024   // d_out (N)
#define RNK 32
#define BM 128
#define BN 512
#define BK 64
#define NKT 16

// ---- Pass 1: W_eff = W + C @ V_r^T, bf16, PRE-SWIZZLED (R10 64KB-chunk) ----
// Chunks [bn(2)][kt(16)] of 64KB = LDS image of a 512row x 64k tile:
// byte(rloc,kloc) = rloc*128 + ((kgrp*16) ^ ((rloc&7)<<4)) + (kloc&7)*2.
__global__ void weff_kernel(const float* __restrict__ W,
                            const float* __restrict__ Vr,
                            const float* __restrict__ C,
                            bf16_t* __restrict__ WeffSw)
{
    const int o  = blockIdx.x;
    const int g  = threadIdx.x;
    const int d0 = g * 8;

    f32x4 cv[8];
#pragma unroll
    for (int q = 0; q < 8; ++q) cv[q] = *(const f32x4*)(C + o * RNK + q * 4);

    const f32x4* wrow = (const f32x4*)(W + (size_t)o * DK + d0);
    f32x4 w0 = wrow[0], w1 = wrow[1];
    float acc[8];
#pragma unroll
    for (int e = 0; e < 4; ++e) { acc[e] = w0[e]; acc[4 + e] = w1[e]; }

#pragma unroll
    for (int e = 0; e < 8; ++e) {
        const f32x4* vre = (const f32x4*)(Vr + (size_t)(d0 + e) * RNK);
        float s = 0.f;
#pragma unroll
        for (int q = 0; q < 8; ++q) {
            f32x4 v = vre[q];
            s += cv[q][0] * v[0] + cv[q][1] * v[1] + cv[q][2] * v[2] + cv[q][3] * v[3];
        }
        acc[e] += s;
    }

    bf16x8 out;
#pragma unroll
    for (int e = 0; e < 8; ++e) out[e] = (bf16_t)acc[e];

    const int bn = o >> 9, rloc = o & 511;
    const int kt = g >> 3, kgrp = g & 7;
    const size_t byte = (size_t)(bn * 16 + kt) * 65536
                      + rloc * 128 + ((kgrp * 16) ^ ((rloc & 7) << 4));
    *(bf16x8*)((char*)WeffSw + byte) = out;
}

// ---- Pass 2: BK=64 all-DMA GEMM, 64 MFMA/wave/iter -------------------------
// B: single 64KB buffer; 8 frags prefetched to regs -> guard barrier ->
//    issueB(t+1) overwrites in place, lands under compute.
// A: fp32 direct DMA (per-lane swizzled src, slot g'=(g&8)|((g&7)^(row&7)),
//    sequential-8 conflict-free), 2-cyclic, issued 1-ahead (full-iter lead).
// End-of-iter vmcnt(0) harmless: all in-flight ops have full-iter lead.
__global__ __launch_bounds__(512, 1) void corrlin_gemm_dma(
    const float* __restrict__ X, const bf16_t* __restrict__ WeffSw,
    const float* __restrict__ bias, float* __restrict__ Out)
{
    __shared__ __align__(16) char smem[131072];
    char* Af0  = smem;                // fp32 A tiles, 32KB each (128r x 64k)
    char* Af1  = smem + 32768;
    char* Blds = smem + 65536;        // bf16 B tile, 64KB (512r x 64k)

    const int tid = threadIdx.x;
    const int b0  = blockIdx.x;
    const int L  = (b0 & 7) * 128 + (b0 >> 3);   // XCD-bijective, nwg=1024
    const int bm = L >> 1;
    const int bn = L & 1;
    const int m0 = bm * BM;

    const int lane = tid & 63;
    const int wn   = tid >> 6;        // 0..7: wave's 64-col slice of BN=512

    f32x4 acc[8][4] = {};             // 128 AGPR

    // A DMA: 2048 granules of 16B. dest d -> row=d>>4, slot=d&15; source
    // granule gs = (slot&8)|((slot&7)^(row&7)); src = x[m0+row][kt*64+gs*4).
    auto issueA = [&](int kt, char* Af) {
#pragma unroll
        for (int c = 0; c < 4; ++c) {
            const int d    = wn * 256 + c * 64 + lane;
            const int row  = d >> 4;
            const int slot = d & 15;
            const int gs   = (slot & 8) | ((slot & 7) ^ (row & 7));
            const float* src = X + (size_t)(m0 + row) * DK + kt * 64 + gs * 4;
            __builtin_amdgcn_global_load_lds(
                (const __attribute__((address_space(1))) void*)src,
                (__attribute__((address_space(3))) void*)(Af + wn * 4096 + c * 1024),
                16, 0, 0);
        }
    };
    auto issueB = [&](int kt) {
        const char* g = (const char*)WeffSw + (size_t)(bn * 16 + kt) * 65536;
#pragma unroll
        for (int c = 0; c < 8; ++c) {
            const int lin = wn * 8192 + c * 1024;
            __builtin_amdgcn_global_load_lds(
                (const __attribute__((address_space(1))) void*)(g + lin + lane * 16),
                (__attribute__((address_space(3))) void*)(Blds + lin),
                16, 0, 0);
        }
    };
    auto readBall = [&](bf16x8* bfr) {
#pragma unroll
        for (int ks = 0; ks < 2; ++ks)
#pragma unroll
            for (int nf = 0; nf < 4; ++nf) {
                const int row  = wn * 64 + nf * 16 + (lane & 15);
                const int kgrp = ks * 4 + (lane >> 4);
                bfr[ks * 4 + nf] = *(const bf16x8*)(
                    Blds + row * 128 + ((kgrp * 16) ^ ((row & 7) << 4)));
            }
    };
    auto compute_ks = [&](const char* Af, int ks, int h, const bf16x8* bfrks) {
        bf16x8 af[4];
        const int g0 = ks * 8 + (lane >> 4) * 2;
#pragma unroll
        for (int i = 0; i < 4; ++i) {
            const int row = (h * 4 + i) * 16 + (lane & 15);
            const int r7  = row & 7;
            const int s0  = (g0 & 8) | ((g0 & 7) ^ r7);
            const int s1  = (g0 & 8) | (((g0 + 1) & 7) ^ r7);
            f32x4 v0 = *(const f32x4*)(Af + row * 256 + s0 * 16);
            f32x4 v1 = *(const f32x4*)(Af + row * 256 + s1 * 16);
#pragma unroll
            for (int j = 0; j < 4; ++j) { af[i][j] = (bf16_t)v0[j]; af[i][4 + j] = (bf16_t)v1[j]; }
        }
        __builtin_amdgcn_s_setprio(1);
#pragma unroll
        for (int i = 0; i < 4; ++i)
#pragma unroll
            for (int nf = 0; nf < 4; ++nf)
                acc[h * 4 + i][nf] = __builtin_amdgcn_mfma_f32_16x16x32_bf16(
                    af[i], bfrks[nf], acc[h * 4 + i][nf], 0, 0, 0);
        __builtin_amdgcn_s_setprio(0);
    };

    // ---- prologue: tile 0 staged ----
    issueA(0, Af0);
    issueB(0);
    asm volatile("s_waitcnt vmcnt(0)" ::: "memory");
    __builtin_amdgcn_s_barrier();

    // main: t = 0..14 (full iters), t = 15 tail
    for (int t = 0; t < NKT - 1; ++t) {
        const char* Ac = (t & 1) ? Af1 : Af0;
        char* An = (t & 1) ? Af0 : Af1;
        issueA(t + 1, An);           // other buffer: safe since t-1's end barrier
        bf16x8 bfr[8];
        readBall(bfr);               // B(t) -> 32 VGPR
        asm volatile("s_waitcnt lgkmcnt(0)" ::: "memory");
        __builtin_amdgcn_s_barrier();   // guard: all waves' B reads done
        issueB(t + 1);               // in-place overwrite, lands under compute
        compute_ks(Ac, 0, 0, bfr);
        compute_ks(Ac, 0, 1, bfr);
        compute_ks(Ac, 1, 0, bfr + 4);
        compute_ks(Ac, 1, 1, bfr + 4);
        asm volatile("s_waitcnt vmcnt(0) lgkmcnt(0)" ::: "memory");
        __builtin_amdgcn_s_barrier();   // tile t+1 fully landed
    }
    {   // t = NKT-1: no issues
        const char* Ac = ((NKT - 1) & 1) ? Af1 : Af0;
        bf16x8 bfr[8];
        readBall(bfr);
        compute_ks(Ac, 0, 0, bfr);
        compute_ks(Ac, 0, 1, bfr);
        compute_ks(Ac, 1, 0, bfr + 4);
        compute_ks(Ac, 1, 1, bfr + 4);
    }
    __syncthreads();                 // LDS free for epilogue reuse

    // ---- epilogue: per-wave LDS transpose -> full-line f32x4 stores --------
    float* tb = (float*)smem + wn * 1280;   // 16x80 f32 per wave
    const int nbase = bn * BN + wn * 64;
    float bv[4];
#pragma unroll
    for (int nf = 0; nf < 4; ++nf) bv[nf] = bias[nbase + nf * 16 + (lane & 15)];

#pragma unroll
    for (int mf = 0; mf < 8; ++mf) {
#pragma unroll
        for (int nf = 0; nf < 4; ++nf)
#pragma unroll
            for (int j = 0; j < 4; ++j) {
                const int r = (lane >> 4) * 4 + j;
                const int c = nf * 16 + (lane & 15);
                tb[r * 80 + c] = acc[mf][nf][j] + bv[nf];
            }
        __syncthreads();
#pragma unroll
        for (int jj = 0; jj < 4; ++jj) {
            const int rr = jj * 4 + (lane >> 4);
            const int cc = (lane & 15) * 4;
            f32x4 v = *(const f32x4*)&tb[rr * 80 + cc];
            *(f32x4*)&Out[(size_t)(m0 + mf * 16 + rr) * DN + nbase + cc] = v;
        }
        __syncthreads();
    }
}

extern "C" void kernel_launch(void* const* d_in, const int* in_sizes, int n_in,
                              void* d_out, int out_size, void* d_ws, size_t ws_size,
                              hipStream_t stream) {
    const float* x  = (const float*)d_in[0];
    const float* W  = (const float*)d_in[1];
    const float* b  = (const float*)d_in[2];
    const float* Vr = (const float*)d_in[3];
    const float* C  = (const float*)d_in[4];
    float* out = (float*)d_out;

    const int M = in_sizes[0] / DK;            // 65536
    bf16_t* WeffSw = (bf16_t*)d_ws;            // 2 MB pre-swizzled W_eff

    weff_kernel<<<DN, 128, 0, stream>>>(W, Vr, C, WeffSw);

    const int mtiles = M / BM;                 // 512
    const int nwg = mtiles * (DN / BN);        // 1024
    corrlin_gemm_dma<<<nwg, 512, 0, stream>>>(x, WeffSw, b, out);
}